// Round 16
// baseline (99.388 us; speedup 1.0000x reference)
//
#include <hip/hip_runtime.h>

// Involution1d fused v9: producer-consumer wave specialization.
// B=16, CH=256, DIM=4096, G=16, K=7, PAD=3, hid=64, K*G=112.
// 512-thr blocks (waves 0-3 compute, 4-7 stage), grid 256 (1 block/CU),
// NT=4 tiles/block (TLC=64).  Stage waves double-buffer x tiles (f16 + halo)
// and keep next-next tile's loads in flight across lgkm-only barriers;
// compute waves run R12's MFMA kerngen + LDS involution.  LDS 93.6 KiB.
#define BB   16
#define CHN  256
#define DIMN 4096
#define KK   7
#define HID  64
#define KGN  112
#define TLC  64        // columns per tile
#define NT   4         // tiles per block
#define XSD  35        // xs row stride in dw (70 halves: 3 halo + 64 + 3 halo)
#define XSH  70        // xs row stride in halves
#define HSTH 70        // hs row stride in halves
#define KSTD 68        // ks row stride in dw (mult of 4 -> aligned uint4)
#define BN_EPS 1e-5f

typedef __fp16 half2_t __attribute__((ext_vector_type(2)));
typedef __fp16 half8   __attribute__((ext_vector_type(8)));
typedef float  f32x4   __attribute__((ext_vector_type(4)));

union U32H2 { unsigned int u; half2_t h; };

static __device__ __forceinline__ unsigned int packf(float a, float b) {
    U32H2 t; t.h = __builtin_amdgcn_cvt_pkrtz(a, b); return t.u;
}
static __device__ __forceinline__ half2_t ash2(unsigned int u) { U32H2 t; t.u = u; return t.h; }
static __device__ __forceinline__ __fp16 u16h(unsigned short u) {
    return __builtin_bit_cast(__fp16, u);
}
static __device__ __forceinline__ unsigned short hu16(__fp16 h) {
    return __builtin_bit_cast(unsigned short, h);
}

// LDS-only barrier: does NOT drain vmcnt -> global loads issued before it
// stay in flight across the barrier (validated in R15, absmax unchanged).
static __device__ __forceinline__ void bar_lds() {
    asm volatile("s_waitcnt lgkmcnt(0)" ::: "memory");
    __builtin_amdgcn_s_barrier();
    __builtin_amdgcn_sched_barrier(0);
}

// ---------------------------------------------------------------------------
__global__ __launch_bounds__(256) void setup_k(
    const float* __restrict__ w1, const float* __restrict__ w2,
    const float* __restrict__ bn_gamma, const float* __restrict__ bn_beta,
    const float* __restrict__ bn_mean,  const float* __restrict__ bn_var,
    __fp16* __restrict__ w1f, __fp16* __restrict__ w2f,
    float* __restrict__ scb, float* __restrict__ shb) {
    int t = blockIdx.x * 256 + threadIdx.x;   // grid covers 16384
    if (t < HID * CHN) w1f[t] = (__fp16)w1[t];
    if (t < KGN * HID) w2f[t] = (__fp16)w2[t];
    if (t < HID) {
        float s = bn_gamma[t] * rsqrtf(bn_var[t] + BN_EPS);
        scb[t] = s;
        shb[t] = bn_beta[t] - bn_mean[t] * s;
    }
}

// ---------------------------------------------------------------------------
template <int OFF>
static __device__ __forceinline__ void extract_kv(const uint4 q[4], float kv[KK][4]) {
#pragma unroll
    for (int k = 0; k < KK; ++k) {
        const int kk = k + OFF;
        const int i  = kk >> 1;
        const int h  = kk & 1;
#pragma unroll
        for (int j = 0; j < 4; ++j) {
            unsigned int u = (&q[i].x)[j];
            half2_t hh = ash2(u);
            kv[k][j] = h ? (float)hh[1] : (float)hh[0];
        }
    }
}

// ---------------------------------------------------------------------------
static __device__ __forceinline__ void load_tile(
    const float* __restrict__ x, int b, int l0, int colq, int chl, int trow,
    float4 v[16], float4& lv, float4& rv) {
    const float* xg = x + ((size_t)b * CHN + chl) * DIMN + l0 + 4 * colq;
#pragma unroll
    for (int i = 0; i < 16; ++i)
        v[i] = *(const float4*)(xg + (size_t)(16 * i) * DIMN);
    const float* xrow = x + ((size_t)b * CHN + trow) * DIMN;
    lv = (l0 > 0) ? *(const float4*)(xrow + l0 - 4)
                  : make_float4(0.f, 0.f, 0.f, 0.f);
    rv = (l0 + TLC < DIMN) ? *(const float4*)(xrow + l0 + TLC)
                           : make_float4(0.f, 0.f, 0.f, 0.f);
}

static __device__ __forceinline__ void store_tile(
    unsigned int* xs, int colq, int chl, int trow,
    const float4 v[16], const float4 lv, const float4 rv) {
    unsigned short* xs16 = (unsigned short*)xs;
#pragma unroll
    for (int i = 0; i < 16; ++i) {
        unsigned short* rp = xs16 + (chl + 16 * i) * XSH + 4 * colq + 3;
        rp[0] = hu16((__fp16)v[i].x);
        *(unsigned int*)(rp + 1) = packf(v[i].y, v[i].z);
        rp[3] = hu16((__fp16)v[i].w);
    }
    unsigned short* hp = xs16 + trow * XSH;
    hp[0]  = hu16((__fp16)lv.y);
    hp[1]  = hu16((__fp16)lv.z);
    hp[2]  = hu16((__fp16)lv.w);
    hp[67] = hu16((__fp16)rv.x);
    hp[68] = hu16((__fp16)rv.y);
    hp[69] = hu16((__fp16)rv.z);
}

// ---------------------------------------------------------------------------
// Fragment maps (16x16x32): A[m][k]: m=lane&15, k=8*((lane>>4)&3)+j;
// B[k][n]: n=lane&15; D[m][n]: n=lane&15, m=4*((lane>>4)&3)+reg.
__global__ __launch_bounds__(512, 1) void fused_k(
    const float* __restrict__ x,
    const __fp16* __restrict__ w1f,
    const float* __restrict__ b1,
    const float* __restrict__ scb, const float* __restrict__ shb,
    const __fp16* __restrict__ w2f,
    const float* __restrict__ b2,
    float* __restrict__ out) {
    __shared__ unsigned int   xs0[CHN * XSD];   // 35840 B
    __shared__ unsigned int   xs1[CHN * XSD];   // 35840 B
    __shared__ unsigned short hsb[HID * HSTH];  // 8960 B
    __shared__ unsigned int   ksb[56 * KSTD];   // 15232 B   (total 93.6 KiB)

    const int t        = threadIdx.x;       // 0..511
    const bool is_stage = (t >= 256);
    const int st       = t & 255;           // role-local id

    const int tid0 = blockIdx.x * NT;       // first tile of this block
    const int b    = tid0 >> 6;             // constant per block (NT | 64)

    if (is_stage) {
        // ================= producer: waves 4..7 =================
        const int colq = st & 15;
        const int chl  = st >> 4;
        float4 v[16], lv, rv;

        // prologue: tile 0 -> xs0; issue tile 1 loads
        load_tile(x, b, (tid0 & 63) * TLC, colq, chl, st, v, lv, rv);
        store_tile(xs0, colq, chl, st, v, lv, rv);
        load_tile(x, b, ((tid0 + 1) & 63) * TLC, colq, chl, st, v, lv, rv);
        bar_lds();

#pragma unroll 2
        for (int tt = 0; tt < NT; ++tt) {
            if (tt + 1 < NT) {
                unsigned int* xsn = ((tt + 1) & 1) ? xs1 : xs0;
                store_tile(xsn, colq, chl, st, v, lv, rv);   // waits vmcnt
                if (tt + 2 < NT)
                    load_tile(x, b, ((tid0 + tt + 2) & 63) * TLC,
                              colq, chl, st, v, lv, rv);     // stays in flight
            }
            bar_lds();   // A
            // (idle during consumer's involution)
            bar_lds();   // B
        }
    } else {
        // ================= consumer: waves 0..3 =================
        const int lane = st & 63;
        const int w    = st >> 6;            // wave 0..3
        const int lr   = st & 15;
        const int lg   = (st >> 4) & 3;
        const int colL = 16 * w + lr;        // wave's column (0..63)

        bar_lds();   // matches producer prologue barrier

#pragma unroll 2
        for (int tt = 0; tt < NT; ++tt) {
            const int l0 = ((tid0 + tt) & 63) * TLC;
            unsigned int*   xs   = (tt & 1) ? xs1 : xs0;
            unsigned short* xs16 = (unsigned short*)xs;

            // ---- Phase 1: h = w1 . x  (4 o-frags x 8 K-steps) ----
            f32x4 acc[4];
#pragma unroll
            for (int of = 0; of < 4; ++of) acc[of] = (f32x4){0.f, 0.f, 0.f, 0.f};

#pragma unroll
            for (int p = 0; p < 8; ++p) {
                half8 bf;
#pragma unroll
                for (int j = 0; j < 8; ++j)
                    bf[j] = u16h(xs16[(32 * p + 8 * lg + j) * XSH + colL + 3]);
#pragma unroll
                for (int of = 0; of < 4; ++of) {
                    half8 af = *(const half8*)(w1f + (16 * of + lr) * CHN + 32 * p + 8 * lg);
                    acc[of] = __builtin_amdgcn_mfma_f32_16x16x32_f16(af, bf, acc[of], 0, 0, 0);
                }
            }

            // ---- bias + relu + BN; h -> hsb (wave-private cols)
#pragma unroll
            for (int of = 0; of < 4; ++of) {
#pragma unroll
                for (int r = 0; r < 4; ++r) {
                    const int o = 16 * of + 4 * lg + r;
                    float hv = fmaxf(acc[of][r] + b1[o], 0.f) * scb[o] + shb[o];
                    hsb[o * HSTH + colL] = hu16((__fp16)hv);
                }
            }

            // ---- Phase 2: kern = w2 . h  (7 r-frags x 2 K-steps) ----
            f32x4 acc2[7];
#pragma unroll
            for (int rf = 0; rf < 7; ++rf) acc2[rf] = (f32x4){0.f, 0.f, 0.f, 0.f};

#pragma unroll
            for (int kx = 0; kx < 2; ++kx) {
                half8 bf;
#pragma unroll
                for (int j = 0; j < 8; ++j)
                    bf[j] = u16h(hsb[(32 * kx + 8 * lg + j) * HSTH + colL]);
#pragma unroll
                for (int rf = 0; rf < 7; ++rf) {
                    half8 af = *(const half8*)(w2f + (16 * rf + lr) * HID + 32 * kx + 8 * lg);
                    acc2[rf] = __builtin_amdgcn_mfma_f32_16x16x32_f16(af, bf, acc2[rf], 0, 0, 0);
                }
            }

            // ---- bias + row-pair pack -> ksb
#pragma unroll
            for (int rf = 0; rf < 7; ++rf) {
#pragma unroll
                for (int p2 = 0; p2 < 2; ++p2) {
                    const int r0 = 16 * rf + 4 * lg + 2 * p2;
                    float k0 = acc2[rf][2 * p2 + 0] + b2[r0 + 0];
                    float k1 = acc2[rf][2 * p2 + 1] + b2[r0 + 1];
                    ksb[(r0 >> 1) * KSTD + colL] = packf(k0, k1);
                }
            }
            bar_lds();   // A

            // ---- Involution: wave w -> groups {4w..4w+3}; taps from LDS ----
            const int q4    = lane & 15;
            const int hi    = lane >> 4;     // 0..3
            const int cbase = 4 * q4;

#pragma unroll
            for (int gi = 0; gi < 4; ++gi) {
                const int g   = 4 * w + gi;  // parity = gi & 1 (4w even)
                const int rpb = (7 * g) >> 1;
                uint4 qq[4];
#pragma unroll
                for (int ii = 0; ii < 4; ++ii)
                    qq[ii] = *(const uint4*)(ksb + (rpb + ii) * KSTD + cbase);
                float kv[KK][4];
                if ((gi & 1) == 0) extract_kv<0>(qq, kv);
                else               extract_kv<1>(qq, kv);

#pragma unroll
                for (int i2 = 0; i2 < 4; ++i2) {
                    const int ch = 16 * g + 4 * i2 + hi;
                    const unsigned int* xr = xs + ch * XSD + (cbase >> 1);
                    unsigned int uu[5];
#pragma unroll
                    for (int j = 0; j < 5; ++j) uu[j] = xr[j];
                    float xv[10];
#pragma unroll
                    for (int r = 0; r < 10; ++r) {
                        half2_t hh = ash2(uu[r >> 1]);
                        xv[r] = (r & 1) ? (float)hh[1] : (float)hh[0];
                    }
                    float o0 = 0.f, o1 = 0.f, o2 = 0.f, o3 = 0.f;
#pragma unroll
                    for (int k = 0; k < KK; ++k) {
                        o0 = fmaf(kv[k][0], xv[k + 0], o0);
                        o1 = fmaf(kv[k][1], xv[k + 1], o1);
                        o2 = fmaf(kv[k][2], xv[k + 2], o2);
                        o3 = fmaf(kv[k][3], xv[k + 3], o3);
                    }
                    *(float4*)(out + ((size_t)b * CHN + ch) * DIMN + l0 + cbase) =
                        make_float4(o0, o1, o2, o3);
                }
            }
            bar_lds();   // B (xs[tt&1] free for producer's tile tt+2)
        }
    }
}

// ---------------------------------------------------------------------------
extern "C" void kernel_launch(void* const* d_in, const int* in_sizes, int n_in,
                              void* d_out, int out_size, void* d_ws, size_t ws_size,
                              hipStream_t stream) {
    (void)in_sizes; (void)n_in; (void)out_size; (void)ws_size;

    const float* x        = (const float*)d_in[0];
    const float* w1       = (const float*)d_in[1];
    const float* b1       = (const float*)d_in[2];
    const float* bn_gamma = (const float*)d_in[3];
    const float* bn_beta  = (const float*)d_in[4];
    const float* bn_mean  = (const float*)d_in[5];
    const float* bn_var   = (const float*)d_in[6];
    const float* w2       = (const float*)d_in[7];
    const float* b2       = (const float*)d_in[8];
    float*       out      = (float*)d_out;

    __fp16* w1f = (__fp16*)d_ws;                 // 16384 f16
    __fp16* w2f = w1f + HID * CHN;               // 7168 f16
    float*  scb = (float*)(w2f + KGN * HID);     // 64
    float*  shb = scb + HID;                     // 64

    setup_k<<<(HID * CHN + 255) / 256, 256, 0, stream>>>(
        w1, w2, bn_gamma, bn_beta, bn_mean, bn_var, w1f, w2f, scb, shb);
    fused_k<<<(BB * (DIMN / TLC)) / NT, 512, 0, stream>>>(
        x, w1f, b1, scb, shb, w2f, b2, out);
}

// Round 17
// 58.563 us; speedup vs baseline: 1.6971x; 1.6971x over previous
//
#include <hip/hip_runtime.h>

// Involution1d fused v10 = R12 + panel-conveyor staging.
// B=16, CH=256, DIM=4096, G=16, K=7, PAD=3, hid=64, K*G=112.
// Block = (b, 64-col tile), 4 waves, 3 blocks/CU (LDS 49.9 KiB).
// Phase-1 K-step p consumes x rows [32p,32p+32); staging is a 2-deep
// conveyor: during step p the loads for panel p+2 are in flight (issued
// after writing panel p+1), crossing one lgkm-only barrier.
#define BB   16
#define CHN  256
#define DIMN 4096
#define KK   7
#define HID  64
#define KGN  112
#define TLC  64        // columns (locations) per block tile
#define XSD  35        // xs row stride in dw (70 halves: 3 halo + 64 + 3 halo)
#define XSH  70        // xs row stride in halves
#define HSTH 70        // hs row stride in halves
#define KSTD 68        // ks row stride in dw (mult of 4 -> aligned uint4)
#define BN_EPS 1e-5f

typedef __fp16 half2_t __attribute__((ext_vector_type(2)));
typedef __fp16 half8   __attribute__((ext_vector_type(8)));
typedef float  f32x4   __attribute__((ext_vector_type(4)));

union U32H2 { unsigned int u; half2_t h; };

static __device__ __forceinline__ unsigned int packf(float a, float b) {
    U32H2 t; t.h = __builtin_amdgcn_cvt_pkrtz(a, b); return t.u;
}
static __device__ __forceinline__ half2_t ash2(unsigned int u) { U32H2 t; t.u = u; return t.h; }
static __device__ __forceinline__ __fp16 u16h(unsigned short u) {
    return __builtin_bit_cast(__fp16, u);
}
static __device__ __forceinline__ unsigned short hu16(__fp16 h) {
    return __builtin_bit_cast(unsigned short, h);
}

// LDS-only barrier: drains lgkmcnt but NOT vmcnt -> global loads issued
// before it stay in flight across the barrier (validated R15/R16).
static __device__ __forceinline__ void bar_lds() {
    asm volatile("s_waitcnt lgkmcnt(0)" ::: "memory");
    __builtin_amdgcn_s_barrier();
    __builtin_amdgcn_sched_barrier(0);
}

// ---------------------------------------------------------------------------
// Convert w1 [64][256] and w2 [112][64] to f16 (layout unchanged); BN affine.
__global__ __launch_bounds__(256) void setup_k(
    const float* __restrict__ w1, const float* __restrict__ w2,
    const float* __restrict__ bn_gamma, const float* __restrict__ bn_beta,
    const float* __restrict__ bn_mean,  const float* __restrict__ bn_var,
    __fp16* __restrict__ w1f, __fp16* __restrict__ w2f,
    float* __restrict__ scb, float* __restrict__ shb) {
    int t = blockIdx.x * 256 + threadIdx.x;   // grid covers 16384
    if (t < HID * CHN) w1f[t] = (__fp16)w1[t];
    if (t < KGN * HID) w2f[t] = (__fp16)w2[t];
    if (t < HID) {
        float s = bn_gamma[t] * rsqrtf(bn_var[t] + BN_EPS);
        scb[t] = s;
        shb[t] = bn_beta[t] - bn_mean[t] * s;
    }
}

// ---------------------------------------------------------------------------
// kern extraction from row-pair-packed uint4 quads; OFF = g&1.
template <int OFF>
static __device__ __forceinline__ void extract_kv(const uint4 q[4], float kv[KK][4]) {
#pragma unroll
    for (int k = 0; k < KK; ++k) {
        const int kk = k + OFF;
        const int i  = kk >> 1;
        const int h  = kk & 1;
#pragma unroll
        for (int j = 0; j < 4; ++j) {
            unsigned int u = (&q[i].x)[j];
            half2_t hh = ash2(u);
            kv[k][j] = h ? (float)hh[1] : (float)hh[0];
        }
    }
}

// ---------------------------------------------------------------------------
// Fused kernel.  Layouts identical to R12:
// xs row (halves): [0..2] left halo, [3..66] cols l0..l0+63, [67..69] right.
// Phases 1/2: wave w owns cols [16w,16w+16) (colL).
// Involution: wave w owns g {4w..4w+3}; lane -> col quad (l&15), ch (l>>4).
// Fragment maps (16x16x32): A[m][k]: m=lane&15, k=8*((lane>>4)&3)+j;
// B[k][n]: n=lane&15; D[m][n]: n=lane&15, m=4*((lane>>4)&3)+reg.
__global__ __launch_bounds__(256, 3) void fused_k(
    const float* __restrict__ x,
    const __fp16* __restrict__ w1f,
    const float* __restrict__ b1,
    const float* __restrict__ scb, const float* __restrict__ shb,
    const __fp16* __restrict__ w2f,
    const float* __restrict__ b2,
    float* __restrict__ out) {
    __shared__ unsigned int xs[CHN * XSD];   // 35840 B (f16 x tile + halo)
    __shared__ unsigned int un[56 * KSTD];   // 15232 B (hs then ks, overlaid)

    unsigned short* xs16 = (unsigned short*)xs;
    unsigned short* hs16 = (unsigned short*)un;
    unsigned int*   ks   = un;

    const int t    = threadIdx.x;          // 0..255
    const int lane = t & 63;
    const int w    = t >> 6;               // wave 0..3
    const int lr   = t & 15;
    const int lg   = (t >> 4) & 3;
    const int b    = blockIdx.x >> 6;
    const int l0   = (blockIdx.x & 63) * TLC;
    const int colL = 16 * w + lr;          // wave's column (0..63)

    // staging ids: colq = col quad (0..15), chl = row-in-halfpanel (0..15)
    const int colq = t & 15;
    const int chl  = t >> 4;
    const float* xgb = x + (size_t)b * CHN * DIMN + l0 + 4 * colq;

    float4 vA[2], vB[2];

#define LOADP(P, V)                                                          \
    { _Pragma("unroll")                                                      \
      for (int i = 0; i < 2; ++i)                                            \
          V[i] = *(const float4*)(xgb + (size_t)(32 * (P) + chl + 16 * i) * DIMN); }

#define WRITEP(P, V)                                                         \
    { _Pragma("unroll")                                                      \
      for (int i = 0; i < 2; ++i) {                                          \
          const int row = 32 * (P) + chl + 16 * i;                           \
          unsigned short* rp = xs16 + row * XSH + 4 * colq + 3;              \
          rp[0] = hu16((__fp16)V[i].x);                                      \
          *(unsigned int*)(rp + 1) = packf(V[i].y, V[i].z);                  \
          rp[3] = hu16((__fp16)V[i].w);                                      \
      } }

#define KSTEP(P)                                                             \
    { half8 bf;                                                              \
      _Pragma("unroll")                                                      \
      for (int j = 0; j < 8; ++j)                                            \
          bf[j] = u16h(xs16[(32 * (P) + 8 * lg + j) * XSH + colL + 3]);      \
      _Pragma("unroll")                                                      \
      for (int of = 0; of < 4; ++of) {                                       \
          half8 af = *(const half8*)(w1f + (16 * of + lr) * CHN + 32 * (P) + 8 * lg); \
          acc[of] = __builtin_amdgcn_mfma_f32_16x16x32_f16(af, bf, acc[of], 0, 0, 0); \
      } }

    // ---- prologue: stage panel 0 + halo; issue panel 1 loads ----
    LOADP(0, vA);
    {
        // halo: thread t covers row t, both sides
        const float* xrow = x + ((size_t)b * CHN + t) * DIMN;
        float4 lv = (l0 > 0) ? *(const float4*)(xrow + l0 - 4)
                             : make_float4(0.f, 0.f, 0.f, 0.f);
        float4 rv = (l0 + TLC < DIMN) ? *(const float4*)(xrow + l0 + TLC)
                                      : make_float4(0.f, 0.f, 0.f, 0.f);
        WRITEP(0, vA);
        unsigned short* hp = xs16 + t * XSH;
        hp[0]  = hu16((__fp16)lv.y);
        hp[1]  = hu16((__fp16)lv.z);
        hp[2]  = hu16((__fp16)lv.w);
        hp[67] = hu16((__fp16)rv.x);
        hp[68] = hu16((__fp16)rv.y);
        hp[69] = hu16((__fp16)rv.z);
    }
    LOADP(1, vB);
    bar_lds();

    // ---- Phase 1: h = w1 . x  (4 o-frags x 8 K-steps, conveyor) ----
    f32x4 acc[4];
#pragma unroll
    for (int of = 0; of < 4; ++of) acc[of] = (f32x4){0.f, 0.f, 0.f, 0.f};

    KSTEP(0); WRITEP(1, vB); LOADP(2, vA); bar_lds();
    KSTEP(1); WRITEP(2, vA); LOADP(3, vB); bar_lds();
    KSTEP(2); WRITEP(3, vB); LOADP(4, vA); bar_lds();
    KSTEP(3); WRITEP(4, vA); LOADP(5, vB); bar_lds();
    KSTEP(4); WRITEP(5, vB); LOADP(6, vA); bar_lds();
    KSTEP(5); WRITEP(6, vA); LOADP(7, vB); bar_lds();
    KSTEP(6); WRITEP(7, vB);               bar_lds();
    KSTEP(7);

    // ---- bias + relu + BN; h -> hs (wave-private cols, same-wave consumer)
#pragma unroll
    for (int of = 0; of < 4; ++of) {
#pragma unroll
        for (int r = 0; r < 4; ++r) {
            const int o = 16 * of + 4 * lg + r;
            float hv = fmaxf(acc[of][r] + b1[o], 0.f) * scb[o] + shb[o];
            hs16[o * HSTH + colL] = hu16((__fp16)hv);
        }
    }

    // ---- Phase 2: kern = w2 . h  (7 r-frags x 2 K-steps) ----
    f32x4 acc2[7];
#pragma unroll
    for (int rf = 0; rf < 7; ++rf) acc2[rf] = (f32x4){0.f, 0.f, 0.f, 0.f};

#pragma unroll
    for (int kx = 0; kx < 2; ++kx) {
        half8 bf;
#pragma unroll
        for (int j = 0; j < 8; ++j)
            bf[j] = u16h(hs16[(32 * kx + 8 * lg + j) * HSTH + colL]);
#pragma unroll
        for (int rf = 0; rf < 7; ++rf) {
            half8 af = *(const half8*)(w2f + (16 * rf + lr) * HID + 32 * kx + 8 * lg);
            acc2[rf] = __builtin_amdgcn_mfma_f32_16x16x32_f16(af, bf, acc2[rf], 0, 0, 0);
        }
    }

    // all hs reads done; barrier before overlaying ks onto the union buffer
    bar_lds();

    // ---- bias + row-pair pack -> ks (overlaid on hs region)
#pragma unroll
    for (int rf = 0; rf < 7; ++rf) {
#pragma unroll
        for (int p = 0; p < 2; ++p) {
            const int r0 = 16 * rf + 4 * lg + 2 * p;
            float k0 = acc2[rf][2 * p + 0] + b2[r0 + 0];
            float k1 = acc2[rf][2 * p + 1] + b2[r0 + 1];
            ks[(r0 >> 1) * KSTD + colL] = packf(k0, k1);
        }
    }
    bar_lds();

    // ---- Involution: wave w -> groups {4w..4w+3}; taps from LDS f16 ----
    const int q4    = lane & 15;
    const int hi    = lane >> 4;           // 0..3
    const int cbase = 4 * q4;              // relative col of this lane's quad

#pragma unroll
    for (int gi = 0; gi < 4; ++gi) {
        const int g   = 4 * w + gi;        // parity = gi & 1 (4w even)
        const int rpb = (7 * g) >> 1;
        uint4 qq[4];
#pragma unroll
        for (int ii = 0; ii < 4; ++ii)
            qq[ii] = *(const uint4*)(ks + (rpb + ii) * KSTD + cbase);
        float kv[KK][4];
        if ((gi & 1) == 0) extract_kv<0>(qq, kv);
        else              extract_kv<1>(qq, kv);

#pragma unroll
        for (int i2 = 0; i2 < 4; ++i2) {
            const int ch = 16 * g + 4 * i2 + hi;
            const unsigned int* xr = xs + ch * XSD + (cbase >> 1);
            unsigned int uu[5];
#pragma unroll
            for (int j = 0; j < 5; ++j) uu[j] = xr[j];
            // halves cbase..cbase+9 of this row; out col cbase+j taps xv[j..j+6]
            float xv[10];
#pragma unroll
            for (int r = 0; r < 10; ++r) {
                half2_t hh = ash2(uu[r >> 1]);
                xv[r] = (r & 1) ? (float)hh[1] : (float)hh[0];
            }
            float o0 = 0.f, o1 = 0.f, o2 = 0.f, o3 = 0.f;
#pragma unroll
            for (int k = 0; k < KK; ++k) {
                o0 = fmaf(kv[k][0], xv[k + 0], o0);
                o1 = fmaf(kv[k][1], xv[k + 1], o1);
                o2 = fmaf(kv[k][2], xv[k + 2], o2);
                o3 = fmaf(kv[k][3], xv[k + 3], o3);
            }
            *(float4*)(out + ((size_t)b * CHN + ch) * DIMN + l0 + cbase) =
                make_float4(o0, o1, o2, o3);
        }
    }
#undef LOADP
#undef WRITEP
#undef KSTEP
}

// ---------------------------------------------------------------------------
extern "C" void kernel_launch(void* const* d_in, const int* in_sizes, int n_in,
                              void* d_out, int out_size, void* d_ws, size_t ws_size,
                              hipStream_t stream) {
    (void)in_sizes; (void)n_in; (void)out_size; (void)ws_size;

    const float* x        = (const float*)d_in[0];
    const float* w1       = (const float*)d_in[1];
    const float* b1       = (const float*)d_in[2];
    const float* bn_gamma = (const float*)d_in[3];
    const float* bn_beta  = (const float*)d_in[4];
    const float* bn_mean  = (const float*)d_in[5];
    const float* bn_var   = (const float*)d_in[6];
    const float* w2       = (const float*)d_in[7];
    const float* b2       = (const float*)d_in[8];
    float*       out      = (float*)d_out;

    __fp16* w1f = (__fp16*)d_ws;                 // 16384 f16
    __fp16* w2f = w1f + HID * CHN;               // 7168 f16
    float*  scb = (float*)(w2f + KGN * HID);     // 64
    float*  shb = scb + HID;                     // 64

    setup_k<<<(HID * CHN + 255) / 256, 256, 0, stream>>>(
        w1, w2, bn_gamma, bn_beta, bn_mean, bn_var, w1f, w2f, scb, shb);
    fused_k<<<BB * (DIMN / TLC), 256, 0, stream>>>(
        x, w1f, b1, scb, shb, w2f, b2, out);
}

// Round 18
// 55.062 us; speedup vs baseline: 1.8050x; 1.0636x over previous
//
#include <hip/hip_runtime.h>

// Involution1d fused v11: R12 semantics at maximum block concurrency.
// B=16, CH=256, DIM=4096, G=16, K=7, PAD=3, hid=64, K*G=112.
// TLC=32, 256-thread 4-wave blocks, LDS 27.5 KiB -> 5 blocks/CU (20 waves).
// Waves split o-frags (ph1) / rf-frags (ph2) instead of columns.
// Scalar halo loads + XCD-chunked block swizzle kill halo over-fetch.
// 4 lgkm-only barriers; x read once, out written once.
#define BB   16
#define CHN  256
#define DIMN 4096
#define KK   7
#define HID  64
#define KGN  112
#define TLC  32        // columns per tile
#define XSD  19        // xs row stride in dw (38 halves: 3 halo + 32 + 3 halo)
#define XSH  38        // xs row stride in halves
#define HSTH 38        // hs row stride in halves
#define KSTD 36        // ks row stride in dw (mult of 4 -> aligned uint4)
#define BN_EPS 1e-5f

typedef __fp16 half2_t __attribute__((ext_vector_type(2)));
typedef __fp16 half8   __attribute__((ext_vector_type(8)));
typedef float  f32x4   __attribute__((ext_vector_type(4)));

union U32H2 { unsigned int u; half2_t h; };

static __device__ __forceinline__ unsigned int packf(float a, float b) {
    U32H2 t; t.h = __builtin_amdgcn_cvt_pkrtz(a, b); return t.u;
}
static __device__ __forceinline__ half2_t ash2(unsigned int u) { U32H2 t; t.u = u; return t.h; }
static __device__ __forceinline__ __fp16 u16h(unsigned short u) {
    return __builtin_bit_cast(__fp16, u);
}
static __device__ __forceinline__ unsigned short hu16(__fp16 h) {
    return __builtin_bit_cast(unsigned short, h);
}

// LDS-only barrier: drains lgkmcnt but NOT vmcnt (validated R15-R17).
static __device__ __forceinline__ void bar_lds() {
    asm volatile("s_waitcnt lgkmcnt(0)" ::: "memory");
    __builtin_amdgcn_s_barrier();
    __builtin_amdgcn_sched_barrier(0);
}

// ---------------------------------------------------------------------------
__global__ __launch_bounds__(256) void setup_k(
    const float* __restrict__ w1, const float* __restrict__ w2,
    const float* __restrict__ bn_gamma, const float* __restrict__ bn_beta,
    const float* __restrict__ bn_mean,  const float* __restrict__ bn_var,
    __fp16* __restrict__ w1f, __fp16* __restrict__ w2f,
    float* __restrict__ scb, float* __restrict__ shb) {
    int t = blockIdx.x * 256 + threadIdx.x;   // grid covers 16384
    if (t < HID * CHN) w1f[t] = (__fp16)w1[t];
    if (t < KGN * HID) w2f[t] = (__fp16)w2[t];
    if (t < HID) {
        float s = bn_gamma[t] * rsqrtf(bn_var[t] + BN_EPS);
        scb[t] = s;
        shb[t] = bn_beta[t] - bn_mean[t] * s;
    }
}

// ---------------------------------------------------------------------------
// kern extraction from row-pair-packed uint4 quads; OFF = g&1.
template <int OFF>
static __device__ __forceinline__ void extract_kv(const uint4 q[4], float kv[KK][4]) {
#pragma unroll
    for (int k = 0; k < KK; ++k) {
        const int kk = k + OFF;
        const int i  = kk >> 1;
        const int h  = kk & 1;
#pragma unroll
        for (int j = 0; j < 4; ++j) {
            unsigned int u = (&q[i].x)[j];
            half2_t hh = ash2(u);
            kv[k][j] = h ? (float)hh[1] : (float)hh[0];
        }
    }
}

// ---------------------------------------------------------------------------
// Fused kernel.  Block = (b, 32-col tile), 4 waves, 5 blocks/CU.
// xs row (halves): [0..2] left halo, [3..34] cols l0..l0+31, [35..37] right.
// Phase 1: wave w owns o-frag w (o in [16w,16w+16)), both col-frags.
// Phase 2: wave w owns rf in {w, w+4 (w<3)}, both col-frags.
// Involution: wave w owns g {4w..4w+3}; lane -> col quad (l&7), ch (l>>3).
// Fragment maps (16x16x32): A[m][k]: m=lane&15, k=8*((lane>>4)&3)+j;
// B[k][n]: n=lane&15; D[m][n]: n=lane&15, m=4*((lane>>4)&3)+reg.
__global__ __launch_bounds__(256, 5) void fused_k(
    const float* __restrict__ x,
    const __fp16* __restrict__ w1f,
    const float* __restrict__ b1,
    const float* __restrict__ scb, const float* __restrict__ shb,
    const __fp16* __restrict__ w2f,
    const float* __restrict__ b2,
    float* __restrict__ out) {
    __shared__ unsigned int xs[CHN * XSD];   // 19456 B (f16 x tile + halo)
    __shared__ unsigned int un[56 * KSTD];   // 8064 B (hs then ks, overlaid)

    unsigned short* xs16 = (unsigned short*)xs;
    unsigned short* hs16 = (unsigned short*)un;
    unsigned int*   ks   = un;

    const int t    = threadIdx.x;          // 0..255
    const int lane = t & 63;
    const int w    = t >> 6;               // wave 0..3
    const int lr   = t & 15;
    const int lg   = (t >> 4) & 3;

    // XCD-chunked swizzle: consecutive logical tiles (sharing halo lines)
    // stay on one XCD's L2.  2048 % 8 == 0 -> bijective.
    const int L  = (blockIdx.x & 7) * 256 + (blockIdx.x >> 3);
    const int b  = L >> 7;                 // 128 tiles per batch
    const int l0 = (L & 127) * TLC;

    // ---- Stage x tile -> LDS f16 (8 float4/thread + 6 scalar halo) ----
    {
        const int colq = t & 7;            // col quad 0..7
        const int chl  = t >> 3;           // 0..31
        const float* xg = x + ((size_t)b * CHN + chl) * DIMN + l0 + 4 * colq;
        float4 v[8];
#pragma unroll
        for (int i = 0; i < 8; ++i)
            v[i] = *(const float4*)(xg + (size_t)(32 * i) * DIMN);
#pragma unroll
        for (int i = 0; i < 8; ++i) {
            unsigned short* rp = xs16 + (chl + 32 * i) * XSH + 4 * colq + 3;
            rp[0] = hu16((__fp16)v[i].x);
            *(unsigned int*)(rp + 1) = packf(v[i].y, v[i].z);
            rp[3] = hu16((__fp16)v[i].w);
        }
        // halo: thread t covers row t, scalar loads (no whole-line overfetch)
        const float* xrow = x + ((size_t)b * CHN + t) * DIMN;
        unsigned short* hp = xs16 + t * XSH;
#pragma unroll
        for (int j = 0; j < 3; ++j) {
            int dl = l0 - 3 + j;
            float lvv = (dl >= 0) ? xrow[dl] : 0.0f;
            hp[j] = hu16((__fp16)lvv);
            int dr = l0 + TLC + j;
            float rvv = (dr < DIMN) ? xrow[dr] : 0.0f;
            hp[35 + j] = hu16((__fp16)rvv);
        }
    }
    bar_lds();

    // ---- Phase 1: h = w1 . x  (wave w: o-frag w, 2 col-frags, 8 K-steps) ----
    f32x4 acc[2];
#pragma unroll
    for (int cf = 0; cf < 2; ++cf) acc[cf] = (f32x4){0.f, 0.f, 0.f, 0.f};

#pragma unroll
    for (int p = 0; p < 8; ++p) {
        half8 af = *(const half8*)(w1f + (16 * w + lr) * CHN + 32 * p + 8 * lg);
#pragma unroll
        for (int cf = 0; cf < 2; ++cf) {
            half8 bf;
#pragma unroll
            for (int j = 0; j < 8; ++j)
                bf[j] = u16h(xs16[(32 * p + 8 * lg + j) * XSH + 16 * cf + lr + 3]);
            acc[cf] = __builtin_amdgcn_mfma_f32_16x16x32_f16(af, bf, acc[cf], 0, 0, 0);
        }
    }

    // ---- bias + relu + BN; h -> hs (rows [16w,16w+16), crosses waves) ----
#pragma unroll
    for (int cf = 0; cf < 2; ++cf) {
#pragma unroll
        for (int r = 0; r < 4; ++r) {
            const int o = 16 * w + 4 * lg + r;
            float hv = fmaxf(acc[cf][r] + b1[o], 0.f) * scb[o] + shb[o];
            hs16[o * HSTH + 16 * cf + lr] = hu16((__fp16)hv);
        }
    }
    bar_lds();   // h complete across waves

    // ---- Phase 2: kern = w2 . h  (wave w: rf in {w, w+4}, 2 K-steps) ----
    const int nrf = (w < 3) ? 2 : 1;
    f32x4 acc2[2][2];
#pragma unroll
    for (int ri = 0; ri < 2; ++ri)
#pragma unroll
        for (int cf = 0; cf < 2; ++cf) acc2[ri][cf] = (f32x4){0.f, 0.f, 0.f, 0.f};

#pragma unroll
    for (int kx = 0; kx < 2; ++kx) {
        half8 bf[2];
#pragma unroll
        for (int cf = 0; cf < 2; ++cf)
#pragma unroll
            for (int j = 0; j < 8; ++j)
                bf[cf][j] = u16h(hs16[(32 * kx + 8 * lg + j) * HSTH + 16 * cf + lr]);
        for (int ri = 0; ri < nrf; ++ri) {
            const int rf = w + 4 * ri;
            half8 af = *(const half8*)(w2f + (16 * rf + lr) * HID + 32 * kx + 8 * lg);
            acc2[ri][0] = __builtin_amdgcn_mfma_f32_16x16x32_f16(af, bf[0], acc2[ri][0], 0, 0, 0);
            acc2[ri][1] = __builtin_amdgcn_mfma_f32_16x16x32_f16(af, bf[1], acc2[ri][1], 0, 0, 0);
        }
    }
    bar_lds();   // all hs reads done before ks overlays the union buffer

    // ---- bias + row-pair pack -> ks (overlaid on hs region)
    for (int ri = 0; ri < nrf; ++ri) {
        const int rf = w + 4 * ri;
#pragma unroll
        for (int cf = 0; cf < 2; ++cf) {
#pragma unroll
            for (int p2 = 0; p2 < 2; ++p2) {
                const int r0 = 16 * rf + 4 * lg + 2 * p2;
                float k0 = acc2[ri][cf][2 * p2 + 0] + b2[r0 + 0];
                float k1 = acc2[ri][cf][2 * p2 + 1] + b2[r0 + 1];
                ks[(r0 >> 1) * KSTD + 16 * cf + lr] = packf(k0, k1);
            }
        }
    }
    bar_lds();

    // ---- Involution: wave w -> groups {4w..4w+3}; taps from LDS f16 ----
    const int q4    = lane & 7;
    const int hi    = lane >> 3;           // 0..7
    const int cbase = 4 * q4;              // relative col of this lane's quad

#pragma unroll
    for (int gi = 0; gi < 4; ++gi) {
        const int g   = 4 * w + gi;        // parity = gi & 1 (4w even)
        const int rpb = (7 * g) >> 1;
        uint4 qq[4];
#pragma unroll
        for (int ii = 0; ii < 4; ++ii)
            qq[ii] = *(const uint4*)(ks + (rpb + ii) * KSTD + cbase);
        float kv[KK][4];
        if ((gi & 1) == 0) extract_kv<0>(qq, kv);
        else               extract_kv<1>(qq, kv);

#pragma unroll
        for (int i2 = 0; i2 < 2; ++i2) {
            const int ch = 16 * g + 8 * i2 + hi;
            const unsigned int* xr = xs + ch * XSD + (cbase >> 1);
            unsigned int uu[5];
#pragma unroll
            for (int j = 0; j < 5; ++j) uu[j] = xr[j];
            // halves cbase..cbase+9; out col cbase+j taps xv[j..j+6]
            float xv[10];
#pragma unroll
            for (int r = 0; r < 10; ++r) {
                half2_t hh = ash2(uu[r >> 1]);
                xv[r] = (r & 1) ? (float)hh[1] : (float)hh[0];
            }
            float o0 = 0.f, o1 = 0.f, o2 = 0.f, o3 = 0.f;
#pragma unroll
            for (int k = 0; k < KK; ++k) {
                o0 = fmaf(kv[k][0], xv[k + 0], o0);
                o1 = fmaf(kv[k][1], xv[k + 1], o1);
                o2 = fmaf(kv[k][2], xv[k + 2], o2);
                o3 = fmaf(kv[k][3], xv[k + 3], o3);
            }
            *(float4*)(out + ((size_t)b * CHN + ch) * DIMN + l0 + cbase) =
                make_float4(o0, o1, o2, o3);
        }
    }
}

// ---------------------------------------------------------------------------
extern "C" void kernel_launch(void* const* d_in, const int* in_sizes, int n_in,
                              void* d_out, int out_size, void* d_ws, size_t ws_size,
                              hipStream_t stream) {
    (void)in_sizes; (void)n_in; (void)out_size; (void)ws_size;

    const float* x        = (const float*)d_in[0];
    const float* w1       = (const float*)d_in[1];
    const float* b1       = (const float*)d_in[2];
    const float* bn_gamma = (const float*)d_in[3];
    const float* bn_beta  = (const float*)d_in[4];
    const float* bn_mean  = (const float*)d_in[5];
    const float* bn_var   = (const float*)d_in[6];
    const float* w2       = (const float*)d_in[7];
    const float* b2       = (const float*)d_in[8];
    float*       out      = (float*)d_out;

    __fp16* w1f = (__fp16*)d_ws;                 // 16384 f16
    __fp16* w2f = w1f + HID * CHN;               // 7168 f16
    float*  scb = (float*)(w2f + KGN * HID);     // 64
    float*  shb = scb + HID;                     // 64

    setup_k<<<(HID * CHN + 255) / 256, 256, 0, stream>>>(
        w1, w2, bn_gamma, bn_beta, bn_mean, bn_var, w1f, w2f, scb, shb);
    fused_k<<<BB * (DIMN / TLC), 256, 0, stream>>>(
        x, w1f, b1, scb, shb, w2f, b2, out);
}

// Round 19
// 51.567 us; speedup vs baseline: 1.9274x; 1.0678x over previous
//
#include <hip/hip_runtime.h>

// Involution1d fused v12: R18 shell + fully vectorized LDS traffic.
// B=16, CH=256, DIM=4096, G=16, K=7, PAD=3, hid=64, K*G=112.
// TLC=32, 256-thread 4-wave blocks, LDS 28.5 KiB -> 5 blocks/CU.
// x staged K-MAJOR (xkt[col][ch], b64 writes / b128 frag reads);
// h transposed (hst[col][o], b64 writes / b128 frag reads);
// involution x-taps from global f32 (L2-hot via XCD-chunked swizzle).
// ~55 LDS instrs/thread (was ~250).  3 lgkm-only barriers.
#define BB   16
#define CHN  256
#define DIMN 4096
#define KK   7
#define HID  64
#define KGN  112
#define TLC  32        // columns per tile
#define XKS  132       // xkt col stride in dw (128 ch-halves/2 + pad)
#define HTS  33        // hst col stride in dw (32 o-halves/2 + pad)
#define KSTD 36        // ks row stride in dw (mult of 4 -> aligned uint4)
#define BN_EPS 1e-5f

typedef __fp16 half2_t __attribute__((ext_vector_type(2)));
typedef __fp16 half8   __attribute__((ext_vector_type(8)));
typedef float  f32x4   __attribute__((ext_vector_type(4)));

union U32H2 { unsigned int u; half2_t h; };

static __device__ __forceinline__ unsigned int packf(float a, float b) {
    U32H2 t; t.h = __builtin_amdgcn_cvt_pkrtz(a, b); return t.u;
}
static __device__ __forceinline__ half2_t ash2(unsigned int u) { U32H2 t; t.u = u; return t.h; }

// LDS-only barrier: drains lgkmcnt but NOT vmcnt (validated R15-R18).
static __device__ __forceinline__ void bar_lds() {
    asm volatile("s_waitcnt lgkmcnt(0)" ::: "memory");
    __builtin_amdgcn_s_barrier();
    __builtin_amdgcn_sched_barrier(0);
}

// ---------------------------------------------------------------------------
__global__ __launch_bounds__(256) void setup_k(
    const float* __restrict__ w1, const float* __restrict__ w2,
    const float* __restrict__ bn_gamma, const float* __restrict__ bn_beta,
    const float* __restrict__ bn_mean,  const float* __restrict__ bn_var,
    __fp16* __restrict__ w1f, __fp16* __restrict__ w2f,
    float* __restrict__ scb, float* __restrict__ shb) {
    int t = blockIdx.x * 256 + threadIdx.x;   // grid covers 16384
    if (t < HID * CHN) w1f[t] = (__fp16)w1[t];
    if (t < KGN * HID) w2f[t] = (__fp16)w2[t];
    if (t < HID) {
        float s = bn_gamma[t] * rsqrtf(bn_var[t] + BN_EPS);
        scb[t] = s;
        shb[t] = bn_beta[t] - bn_mean[t] * s;
    }
}

// ---------------------------------------------------------------------------
// kern extraction from row-pair-packed uint4 quads; OFF = g&1.
template <int OFF>
static __device__ __forceinline__ void extract_kv(const uint4 q[4], float kv[KK][4]) {
#pragma unroll
    for (int k = 0; k < KK; ++k) {
        const int kk = k + OFF;
        const int i  = kk >> 1;
        const int h  = kk & 1;
#pragma unroll
        for (int j = 0; j < 4; ++j) {
            unsigned int u = (&q[i].x)[j];
            half2_t hh = ash2(u);
            kv[k][j] = h ? (float)hh[1] : (float)hh[0];
        }
    }
}

// ---------------------------------------------------------------------------
// Fused kernel.  Block = (b, 32-col tile), 4 waves, 5 blocks/CU.
// xkt[col][ch]: dw = col*132 + ((ch>>1) ^ ((col&7)<<4))   (f16 pairs over ch)
// hst[col][o] : dw = col*33  + (o>>1)                     (f16 pairs over o)
// Phase 1: wave w owns o-frag w, 2 col-frags.  Phase 2: rf in {w, w+4 (w<3)}.
// Involution: wave w owns g {4w..4w+3}; lane -> col quad (l&7), ch (l>>3);
// x taps read from GLOBAL f32 (L2-hot).
// Fragment maps (16x16x32): A[m][k]: m=lane&15, k=8*(lane>>4)+j;
// B[k][n]: n=lane&15; D[m][n]: n=lane&15, m=4*(lane>>4)+reg.
__global__ __launch_bounds__(256, 5) void fused_k(
    const float* __restrict__ x,
    const __fp16* __restrict__ w1f,
    const float* __restrict__ b1,
    const float* __restrict__ scb, const float* __restrict__ shb,
    const __fp16* __restrict__ w2f,
    const float* __restrict__ b2,
    float* __restrict__ out) {
    __shared__ unsigned int xkt[TLC * XKS];   // 16896 B
    __shared__ unsigned int hst[TLC * HTS];   // 4224 B
    __shared__ unsigned int ks[56 * KSTD];    // 8064 B   (total 28.5 KiB)

    const unsigned short* xkt16 = (const unsigned short*)xkt;
    const unsigned short* hst16 = (const unsigned short*)hst;

    const int t    = threadIdx.x;          // 0..255
    const int lane = t & 63;
    const int w    = t >> 6;               // wave 0..3
    const int lr   = t & 15;
    const int lg   = (t >> 4) & 3;

    // XCD-chunked swizzle (2048 % 8 == 0 -> bijective); neighbor tiles share
    // an XCD's L2 -> inv's global x re-read is L2-hot.
    const int L  = (blockIdx.x & 7) * 256 + (blockIdx.x >> 3);
    const int b  = L >> 7;                 // 128 tiles per batch
    const int l0 = (L & 127) * TLC;

    // ---- Stage x -> xkt (k-major): 32 scalar global loads, 8 b64 writes ----
    {
        const int col = t & 31;
        const int chq = t >> 5;            // 0..7
        const int xsw = (col & 7) << 4;
        const float* xg = x + (size_t)b * CHN * DIMN + l0 + col;
#pragma unroll
        for (int i = 0; i < 8; ++i) {
            const int ch0 = 4 * chq + 32 * i;
            float f0 = xg[(size_t)(ch0 + 0) * DIMN];
            float f1 = xg[(size_t)(ch0 + 1) * DIMN];
            float f2 = xg[(size_t)(ch0 + 2) * DIMN];
            float f3 = xg[(size_t)(ch0 + 3) * DIMN];
            uint2 u;
            u.x = packf(f0, f1);
            u.y = packf(f2, f3);
            *(uint2*)&xkt[col * XKS + (((ch0 >> 1)) ^ xsw)] = u;
        }
    }
    bar_lds();

    // ---- Phase 1: h = w1 . x  (wave w: o-frag w, 2 col-frags, 8 K-steps) ----
    f32x4 acc[2];
#pragma unroll
    for (int cf = 0; cf < 2; ++cf) acc[cf] = (f32x4){0.f, 0.f, 0.f, 0.f};

#pragma unroll
    for (int p = 0; p < 8; ++p) {
        half8 af = *(const half8*)(w1f + (16 * w + lr) * CHN + 32 * p + 8 * lg);
#pragma unroll
        for (int cf = 0; cf < 2; ++cf) {
            const int col = 16 * cf + lr;
            const int dwo = col * XKS + ((16 * p + 4 * lg) ^ ((col & 7) << 4));
            half8 bf = *(const half8*)(xkt16 + 2 * dwo);   // 1x ds_read_b128
            acc[cf] = __builtin_amdgcn_mfma_f32_16x16x32_f16(af, bf, acc[cf], 0, 0, 0);
        }
    }

    // ---- bias+relu+BN; h -> hst[col][o] (2x ds_write_b64, crosses waves) ----
#pragma unroll
    for (int cf = 0; cf < 2; ++cf) {
        const int col = 16 * cf + lr;
        float hv[4];
#pragma unroll
        for (int r = 0; r < 4; ++r) {
            const int o = 16 * w + 4 * lg + r;
            hv[r] = fmaxf(acc[cf][r] + b1[o], 0.f) * scb[o] + shb[o];
        }
        uint2 u;
        u.x = packf(hv[0], hv[1]);
        u.y = packf(hv[2], hv[3]);
        *(uint2*)&hst[col * HTS + 8 * w + 2 * lg] = u;
    }
    bar_lds();

    // ---- Phase 2: kern = w2 . h  (wave w: rf in {w, w+4}, 2 K-steps) ----
    const int nrf = (w < 3) ? 2 : 1;
    f32x4 acc2[2][2];
#pragma unroll
    for (int ri = 0; ri < 2; ++ri)
#pragma unroll
        for (int cf = 0; cf < 2; ++cf) acc2[ri][cf] = (f32x4){0.f, 0.f, 0.f, 0.f};

#pragma unroll
    for (int kx = 0; kx < 2; ++kx) {
        half8 bf[2];
#pragma unroll
        for (int cf = 0; cf < 2; ++cf) {
            const int col = 16 * cf + lr;
            bf[cf] = *(const half8*)(hst16 + 2 * (col * HTS + 16 * kx + 4 * lg));
        }
        for (int ri = 0; ri < nrf; ++ri) {
            const int rf = w + 4 * ri;
            half8 af = *(const half8*)(w2f + (16 * rf + lr) * HID + 32 * kx + 8 * lg);
            acc2[ri][0] = __builtin_amdgcn_mfma_f32_16x16x32_f16(af, bf[0], acc2[ri][0], 0, 0, 0);
            acc2[ri][1] = __builtin_amdgcn_mfma_f32_16x16x32_f16(af, bf[1], acc2[ri][1], 0, 0, 0);
        }
    }

    // ---- bias + row-pair pack -> ks ----
    for (int ri = 0; ri < nrf; ++ri) {
        const int rf = w + 4 * ri;
#pragma unroll
        for (int cf = 0; cf < 2; ++cf) {
#pragma unroll
            for (int p2 = 0; p2 < 2; ++p2) {
                const int r0 = 16 * rf + 4 * lg + 2 * p2;
                float k0 = acc2[ri][cf][2 * p2 + 0] + b2[r0 + 0];
                float k1 = acc2[ri][cf][2 * p2 + 1] + b2[r0 + 1];
                ks[(r0 >> 1) * KSTD + 16 * cf + lr] = packf(k0, k1);
            }
        }
    }
    bar_lds();

    // ---- Involution: wave w -> groups {4w..4w+3}; x taps from GLOBAL f32 ----
    const int q4    = lane & 7;
    const int hi    = lane >> 3;           // 0..7
    const int cbase = 4 * q4;
    const int col0  = l0 + cbase;

#pragma unroll
    for (int gi = 0; gi < 4; ++gi) {
        const int g   = 4 * w + gi;        // parity = gi & 1 (4w even)
        const int rpb = (7 * g) >> 1;
        uint4 qq[4];
#pragma unroll
        for (int ii = 0; ii < 4; ++ii)
            qq[ii] = *(const uint4*)(ks + (rpb + ii) * KSTD + cbase);
        float kv[KK][4];
        if ((gi & 1) == 0) extract_kv<0>(qq, kv);
        else               extract_kv<1>(qq, kv);

#pragma unroll
        for (int i2 = 0; i2 < 2; ++i2) {
            const int ch = 16 * g + 8 * i2 + hi;
            const float* xrow = x + ((size_t)b * CHN + ch) * DIMN;
            float4 fa = *(const float4*)(xrow + (col0 > 0 ? col0 - 4 : 0));
            float4 fb = *(const float4*)(xrow + col0);
            float4 fc = *(const float4*)(xrow + (col0 + 4 < DIMN ? col0 + 4 : DIMN - 4));

            float xr[10] = { fa.y, fa.z, fa.w, fb.x, fb.y, fb.z, fb.w, fc.x, fc.y, fc.z };
            if (col0 == 0)        { xr[0] = 0.f; xr[1] = 0.f; xr[2] = 0.f; }
            if (col0 == DIMN - 4) { xr[7] = 0.f; xr[8] = 0.f; xr[9] = 0.f; }

            float o0 = 0.f, o1 = 0.f, o2 = 0.f, o3 = 0.f;
#pragma unroll
            for (int k = 0; k < KK; ++k) {
                o0 = fmaf(kv[k][0], xr[k + 0], o0);
                o1 = fmaf(kv[k][1], xr[k + 1], o1);
                o2 = fmaf(kv[k][2], xr[k + 2], o2);
                o3 = fmaf(kv[k][3], xr[k + 3], o3);
            }
            *(float4*)(out + ((size_t)b * CHN + ch) * DIMN + col0) =
                make_float4(o0, o1, o2, o3);
        }
    }
}

// ---------------------------------------------------------------------------
extern "C" void kernel_launch(void* const* d_in, const int* in_sizes, int n_in,
                              void* d_out, int out_size, void* d_ws, size_t ws_size,
                              hipStream_t stream) {
    (void)in_sizes; (void)n_in; (void)out_size; (void)ws_size;

    const float* x        = (const float*)d_in[0];
    const float* w1       = (const float*)d_in[1];
    const float* b1       = (const float*)d_in[2];
    const float* bn_gamma = (const float*)d_in[3];
    const float* bn_beta  = (const float*)d_in[4];
    const float* bn_mean  = (const float*)d_in[5];
    const float* bn_var   = (const float*)d_in[6];
    const float* w2       = (const float*)d_in[7];
    const float* b2       = (const float*)d_in[8];
    float*       out      = (float*)d_out;

    __fp16* w1f = (__fp16*)d_ws;                 // 16384 f16
    __fp16* w2f = w1f + HID * CHN;               // 7168 f16
    float*  scb = (float*)(w2f + KGN * HID);     // 64
    float*  shb = scb + HID;                     // 64

    setup_k<<<(HID * CHN + 255) / 256, 256, 0, stream>>>(
        w1, w2, bn_gamma, bn_beta, bn_mean, bn_var, w1f, w2f, scb, shb);
    fused_k<<<BB * (DIMN / TLC), 256, 0, stream>>>(
        x, w1f, b1, scb, shb, w2f, b2, out);
}